// Round 10
// baseline (723.666 us; speedup 1.0000x reference)
//
#include <hip/hip_runtime.h>
#include <hip/hip_cooperative_groups.h>

namespace cg = cooperative_groups;

#define N_NODES 50000
#define N_EDGES 800000
#define E_TOT   (N_EDGES + N_NODES)   // 850000, self-loops appended at end
#define SCAN_B  ((N_NODES + 255) / 256)  // 196

using bfrag = __attribute__((ext_vector_type(8))) short;
using f32x4 = __attribute__((ext_vector_type(4))) float;

// ---------------------------------------------------------------- bf16 helpers
__device__ __forceinline__ float bflo(unsigned int p) {
  union { unsigned int u; float f; } v; v.u = p << 16; return v.f;
}
__device__ __forceinline__ float bfhi(unsigned int p) {
  union { unsigned int u; float f; } v; v.u = p & 0xFFFF0000u; return v.f;
}
__device__ __forceinline__ unsigned short f2bf(float f) {
  union { float f; unsigned int u; } v; v.f = f;
  unsigned int r = v.u + 0x7FFFu + ((v.u >> 16) & 1u);
  return (unsigned short)(r >> 16);
}
__device__ __forceinline__ void unpack8(uint4 u, float* hv) {
  hv[0] = bflo(u.x); hv[1] = bfhi(u.x);
  hv[2] = bflo(u.y); hv[3] = bfhi(u.y);
  hv[4] = bflo(u.z); hv[5] = bfhi(u.z);
  hv[6] = bflo(u.w); hv[7] = bfhi(u.w);
}

// ------------------------------------------------- W-only conversions (tiny)
#define CW1 (128 * 256)
#define CW2 (CW1 + 256 * 128)
__global__ void k_convW(const float* __restrict__ W1, const float* __restrict__ W2,
                        unsigned short* __restrict__ W1t, unsigned short* __restrict__ W2t) {
  int i = blockIdx.x * blockDim.x + threadIdx.x;
  if (i < CW1) {
    int k = i >> 8, n = i & 255;
    W1t[n * 128 + k] = f2bf(W1[i]);
  } else if (i < CW2) {
    int j = i - CW1;
    int k = j >> 7, n = j & 127;
    W2t[n * 256 + k] = f2bf(W2[j]);
  }
}

// ---------------------------------------------- cooperative one-shot CSR build
// zero -> hist -> per-block scan -> block0 scan -> offsets -> scatter,
// grid.sync() between phases. Grid 1024x256 (co-resident: 4 blocks/CU).
__global__ void k_csr(const int* __restrict__ ei, int* __restrict__ cnt,
                      int* __restrict__ rowptr, int* __restrict__ cursor,
                      int* __restrict__ csr, int* __restrict__ bsum) {
  cg::grid_group grid = cg::this_grid();
  __shared__ int s[256];
  const int T = 1024 * 256;
  int tid = blockIdx.x * 256 + threadIdx.x;
  // phase 0: zero counts
  for (int i = tid; i < N_NODES; i += T) cnt[i] = 0;
  grid.sync();
  // phase 1: histogram
  for (int e = tid; e < E_TOT; e += T) {
    int d = (e < N_EDGES) ? ei[N_EDGES + e] : (e - N_EDGES);
    atomicAdd(&cnt[d], 1);
  }
  grid.sync();
  // phase 2: per-block exclusive scan (blocks 0..SCAN_B-1, 256 nodes each)
  if (blockIdx.x < SCAN_B) {
    int t = threadIdx.x;
    int i = blockIdx.x * 256 + t;
    int v = (i < N_NODES) ? cnt[i] : 0;
    s[t] = v;
    __syncthreads();
    for (int off = 1; off < 256; off <<= 1) {
      int x = (t >= off) ? s[t - off] : 0;
      __syncthreads();
      s[t] += x;
      __syncthreads();
    }
    if (i < N_NODES) rowptr[i] = s[t] - v;   // block-local exclusive
    if (t == 255) bsum[blockIdx.x] = s[255]; // block total
  }
  grid.sync();
  // phase 3: block 0 scans the block totals
  if (blockIdx.x == 0) {
    int t = threadIdx.x;
    int v = (t < SCAN_B) ? bsum[t] : 0;
    s[t] = v;
    __syncthreads();
    for (int off = 1; off < 256; off <<= 1) {
      int x = (t >= off) ? s[t - off] : 0;
      __syncthreads();
      s[t] += x;
      __syncthreads();
    }
    if (t < SCAN_B) bsum[t] = s[t] - v;      // exclusive block offsets
  }
  grid.sync();
  // phase 4: global offsets + cursor init
  for (int i = tid; i < N_NODES; i += T) {
    int r = rowptr[i] + bsum[i >> 8];
    rowptr[i] = r; cursor[i] = r;
  }
  if (tid == 0) rowptr[N_NODES] = E_TOT;
  grid.sync();
  // phase 5: scatter
  for (int e = tid; e < E_TOT; e += T) {
    int sj, d;
    if (e < N_EDGES) { sj = ei[e]; d = ei[N_EDGES + e]; }
    else             { sj = d = e - N_EDGES; }
    int pos = atomicAdd(&cursor[d], 1);
    csr[pos] = sj;
  }
}

// ------------------------------------------- MFMA bf16 GEMM + fused epilogue
// ROWS rows per block, all H heads full-width. A32: A is fp32, convert
// in-register during the A-fragment load (kills the x->bf16 pre-pass).
template <int KD, int H, int ROWS, bool A32>
__global__ __launch_bounds__(ROWS * 4) void k_gemm_mfma(
    const void* __restrict__ Aq, const unsigned short* __restrict__ Wt,
    const float* __restrict__ atts, const float* __restrict__ attd,
    unsigned short* __restrict__ hq, float* __restrict__ aS,
    float* __restrict__ aD, int M) {
  constexpr int NN = H * 64;
  constexpr int KH = KD / 2;              // K per half
  constexpr int GR = KH / 8;              // 16B granules per col per half
  constexpr int T  = ROWS * 4;            // threads
  __shared__ unsigned short Bts[NN * KH]; // 32 KB
  int t = threadIdx.x;
  int lane = t & 63;
  int w = t >> 6;
  int arow = blockIdx.x * ROWS + w * 16 + (lane & 15);
  int arow_c = arow < M ? arow : M - 1;
  const unsigned short* ArowB = (const unsigned short*)Aq + (size_t)arow_c * KD;
  const float*          ArowF = (const float*)Aq + (size_t)arow_c * KD;

  f32x4 acc[NN / 16] = {};
  #pragma unroll
  for (int half = 0; half < 2; ++half) {
    if (half) __syncthreads();
    #pragma unroll
    for (int c = 0; c < NN * KH / 8 / T; ++c) {
      int chunk = t + c * T;
      int col = chunk / GR;
      int kc  = chunk % GR;
      uint4 v = *(const uint4*)&Wt[(size_t)col * KD + half * KH + kc * 8];
      int swz = kc ^ (col & 7);
      *(uint4*)&Bts[col * KH + swz * 8] = v;
    }
    __syncthreads();
    for (int k0 = 0; k0 < KH; k0 += 32) {
      int gl = (k0 >> 3) + (lane >> 4);
      bfrag a;
      if constexpr (A32) {
        const float* Ap = ArowF + half * KH + gl * 8;
        float4 v0 = *(const float4*)Ap;
        float4 v1 = *(const float4*)(Ap + 4);
        a[0] = (short)f2bf(v0.x); a[1] = (short)f2bf(v0.y);
        a[2] = (short)f2bf(v0.z); a[3] = (short)f2bf(v0.w);
        a[4] = (short)f2bf(v1.x); a[5] = (short)f2bf(v1.y);
        a[6] = (short)f2bf(v1.z); a[7] = (short)f2bf(v1.w);
      } else {
        a = *(const bfrag*)&ArowB[half * KH + gl * 8];
      }
      #pragma unroll
      for (int cf = 0; cf < NN / 16; ++cf) {
        int col = cf * 16 + (lane & 15);
        int gs = gl ^ (col & 7);
        bfrag b = *(const bfrag*)&Bts[col * KH + gs * 8];
        acc[cf] = __builtin_amdgcn_mfma_f32_16x16x32_bf16(a, b, acc[cf], 0, 0, 0);
      }
    }
  }

  float ws_[NN / 16], wd_[NN / 16];
  #pragma unroll
  for (int cf = 0; cf < NN / 16; ++cf) {
    ws_[cf] = atts[cf * 16 + (lane & 15)];
    wd_[cf] = attd[cf * 16 + (lane & 15)];
  }
  int orow0 = blockIdx.x * ROWS + w * 16 + (lane >> 4) * 4;
  #pragma unroll
  for (int hh = 0; hh < H; ++hh) {
    float ps[4] = {}, pd[4] = {};
    #pragma unroll
    for (int c4 = 0; c4 < 4; ++c4) {
      int cf = hh * 4 + c4;
      #pragma unroll
      for (int i = 0; i < 4; ++i) {
        ps[i] += acc[cf][i] * ws_[cf];
        pd[i] += acc[cf][i] * wd_[cf];
      }
    }
    #pragma unroll
    for (int off = 1; off < 16; off <<= 1)
      #pragma unroll
      for (int i = 0; i < 4; ++i) {
        ps[i] += __shfl_xor(ps[i], off);
        pd[i] += __shfl_xor(pd[i], off);
      }
    if ((lane & 15) == 0)
      #pragma unroll
      for (int i = 0; i < 4; ++i) {
        int r = orow0 + i;
        if (r < M) {
          aS[(size_t)r * H + hh] = ps[i];
          aD[(size_t)r * H + hh] = pd[i];
        }
      }
  }
  #pragma unroll
  for (int i = 0; i < 4; ++i) {
    int r = orow0 + i;
    if (r < M)
      #pragma unroll
      for (int cf = 0; cf < NN / 16; ++cf)
        hq[(size_t)r * NN + cf * 16 + (lane & 15)] = f2bf(acc[cf][i]);
  }
}

// -------------- edge-softmax + aggregate, NO-MAX softmax. Phase 0 stages
// j + w=exp(leaky(aS+aD)), per-lane denom. Phase 1: predication-free 2D
// gather. PROJ3 fuses the layer-3 projection into the epilogue.
template <int H, bool ELU, bool OBF, bool PROJ3>
__global__ __launch_bounds__(256) void k_aggr(
    const int* __restrict__ rowptr, const int* __restrict__ csr,
    const unsigned short* __restrict__ hq,
    const float* __restrict__ aS, const float* __restrict__ aD,
    const float* __restrict__ bias, void* __restrict__ outv,
    const float* __restrict__ W3, const float* __restrict__ s3,
    const float* __restrict__ d3, float* __restrict__ h3o,
    float* __restrict__ a3so, float* __restrict__ a3do) {
  constexpr int CAP = 64;
  constexpr int C = H * 64;
  constexpr int EPW = 512 / C;      // edges per wave instr: H=4 -> 2, H=2 -> 4
  constexpr int LPE = 64 / EPW;     // lanes per edge
  __shared__ int   jls[4][CAP];
  __shared__ float wls[4][CAP * H];
  int n    = (int)((blockIdx.x * (size_t)blockDim.x + threadIdx.x) >> 6);
  int lane = threadIdx.x & 63;
  int wsl  = threadIdx.x >> 6;
  if (n >= N_NODES) return;
  int* jl  = jls[wsl];
  float* wl = wls[wsl];
  int cg  = lane & (LPE - 1);       // channel group: channels cg*8 .. cg*8+7
  int sub = lane / LPE;             // which edge of the EPW-pack
  int hlc = cg >> 3;                // head owning this lane's channels

  float ad[H];
  #pragma unroll
  for (int h = 0; h < H; ++h) ad[h] = aD[(size_t)n * H + h];

  int lo = rowptr[n], deg = rowptr[n + 1] - lo;
  float sl[H] = {};                 // per-lane partial denominators
  float acc8[8] = {};

  for (int c0 = 0; c0 < deg; c0 += CAP) {
    int cl = deg - c0; if (cl > CAP) cl = CAP;
    int clp = (cl + EPW - 1) & ~(EPW - 1);   // pad to EPW multiple
    // ---- phase 0: stage j + w = exp(leaky(aS+aD)); accumulate denom
    for (int kk = lane; kk < clp; kk += 64) {
      bool v = kk < cl;
      int j = v ? csr[lo + c0 + kk] : n;     // pad: self (valid row), w=0
      jl[kk] = j;
      float e[H];
      if constexpr (H == 4) {
        float4 a4 = *(const float4*)&aS[(size_t)j * 4];
        e[0] = a4.x; e[1] = a4.y; e[2] = a4.z; e[3] = a4.w;
      } else {
        float2 a2 = *(const float2*)&aS[(size_t)j * 2];
        e[0] = a2.x; e[1] = a2.y;
      }
      #pragma unroll
      for (int h = 0; h < H; ++h) {
        float ev = e[h] + ad[h];
        ev = ev > 0.f ? ev : 0.2f * ev;
        float w = v ? __expf(ev) : 0.f;
        sl[h] += w;
        e[h] = w;
      }
      if constexpr (H == 4)
        *(float4*)&wl[kk * 4] = make_float4(e[0], e[1], e[2], e[3]);
      else
        *(float2*)&wl[kk * 2] = make_float2(e[0], e[1]);
    }
    __builtin_amdgcn_wave_barrier();
    // ---- phase 1: predication-free 2D gather-accumulate
    #pragma unroll 4
    for (int k = 0; k < clp; k += EPW) {
      int idx = k + sub;
      int j = jl[idx];
      float wgt = wl[idx * H + hlc];
      uint4 u = *(const uint4*)&hq[(size_t)j * C + cg * 8];
      float hv[8];
      unpack8(u, hv);
      #pragma unroll
      for (int i = 0; i < 8; ++i) acc8[i] += wgt * hv[i];
    }
    __builtin_amdgcn_wave_barrier();
  }

  // single denominator reduction per node (all lanes end with totals)
  #pragma unroll
  for (int off = 1; off < 64; off <<= 1)
    #pragma unroll
    for (int h = 0; h < H; ++h) sl[h] += __shfl_xor(sl[h], off);

  // fold the EPW edge-subgroups: all lanes end with folded totals
  #pragma unroll
  for (int i = 0; i < 8; ++i) {
    if constexpr (EPW == 4) acc8[i] += __shfl_xor(acc8[i], 16);
    acc8[i] += __shfl_xor(acc8[i], 32);
  }

  float inv = 1.f / sl[hlc];
  float o[8];
  #pragma unroll
  for (int i = 0; i < 8; ++i) {
    float v = acc8[i] * inv + bias[cg * 8 + i];
    if (ELU) v = v > 0.f ? v : __expf(v) - 1.f;
    o[i] = v;
  }

  if constexpr (PROJ3) {
    // fused layer-3 projection: h3 = o . W3 (128x2), a3s/a3d from h3
    float a0 = 0.f, a1 = 0.f;
    #pragma unroll
    for (int i = 0; i < 8; ++i) {
      int c = cg * 8 + i;
      a0 += o[i] * W3[c * 2 + 0];
      a1 += o[i] * W3[c * 2 + 1];
    }
    #pragma unroll
    for (int off = 1; off < 16; off <<= 1) {
      a0 += __shfl_xor(a0, off);
      a1 += __shfl_xor(a1, off);
    }
    if (lane == 0) {
      h3o[(size_t)n * 2]     = a0;
      h3o[(size_t)n * 2 + 1] = a1;
      a3so[n] = a0 * s3[0] + a1 * s3[1];
      a3do[n] = a0 * d3[0] + a1 * d3[1];
    }
  } else if (sub == 0) {
    size_t idx = (size_t)n * C + cg * 8;
    if constexpr (OBF) {
      unsigned short* outp = (unsigned short*)outv;
      uint4 r;
      r.x = (unsigned int)f2bf(o[0]) | ((unsigned int)f2bf(o[1]) << 16);
      r.y = (unsigned int)f2bf(o[2]) | ((unsigned int)f2bf(o[3]) << 16);
      r.z = (unsigned int)f2bf(o[4]) | ((unsigned int)f2bf(o[5]) << 16);
      r.w = (unsigned int)f2bf(o[6]) | ((unsigned int)f2bf(o[7]) << 16);
      *(uint4*)&outp[idx] = r;
    } else {
      float* outp = (float*)outv;
      *(float4*)&outp[idx]     = make_float4(o[0], o[1], o[2], o[3]);
      *(float4*)&outp[idx + 4] = make_float4(o[4], o[5], o[6], o[7]);
    }
  }
}

// --------------------------------------------------------- layer-3 aggregate
__global__ void k_aggr3(const int* __restrict__ rowptr, const int* __restrict__ csr,
                        const float* __restrict__ h3, const float* __restrict__ a3s,
                        const float* __restrict__ a3d, const float* __restrict__ b3,
                        float* __restrict__ out) {
  int n = blockIdx.x * blockDim.x + threadIdx.x;
  if (n >= N_NODES) return;
  float adv = a3d[n];
  float s = 0.f, acc0 = 0.f, acc1 = 0.f;
  int lo = rowptr[n], hi = rowptr[n + 1];
  for (int k = lo; k < hi; ++k) {
    int j = csr[k];
    float e = a3s[j] + adv;
    e = e > 0.f ? e : 0.2f * e;
    float w = __expf(e);           // no-max softmax (logits small)
    float2 h = *(const float2*)&h3[(size_t)j * 2];
    s += w; acc0 += w * h.x; acc1 += w * h.y;
  }
  float o0 = acc0 / s + b3[0];
  float o1 = acc1 / s + b3[1];
  float mx = fmaxf(o0, o1);
  float l  = logf(__expf(o0 - mx) + __expf(o1 - mx));
  out[(size_t)n * 2]     = o0 - mx - l;
  out[(size_t)n * 2 + 1] = o1 - mx - l;
}

// ---------------------------------------------------------------- launcher
extern "C" void kernel_launch(void* const* d_in, const int* in_sizes, int n_in,
                              void* d_out, int out_size, void* d_ws, size_t ws_size,
                              hipStream_t stream) {
  const float* x   = (const float*)d_in[0];
  const int*   ei  = (const int*)d_in[1];
  const float* W1  = (const float*)d_in[2];
  const float* as1 = (const float*)d_in[3];
  const float* ad1 = (const float*)d_in[4];
  const float* b1  = (const float*)d_in[5];
  const float* W2  = (const float*)d_in[6];
  const float* as2 = (const float*)d_in[7];
  const float* ad2 = (const float*)d_in[8];
  const float* b2  = (const float*)d_in[9];
  const float* W3  = (const float*)d_in[10];
  const float* as3 = (const float*)d_in[11];
  const float* ad3 = (const float*)d_in[12];
  const float* b3  = (const float*)d_in[13];
  float* out = (float*)d_out;

  char* p = (char*)d_ws;
  auto alloc = [&](size_t bytes) -> char* {
    char* r = p; p += (bytes + 255) & ~(size_t)255; return r;
  };
  int*   cnt    = (int*)alloc((size_t)N_NODES * 4);
  int*   rowptr = (int*)alloc((size_t)(N_NODES + 1) * 4);
  int*   cursor = (int*)alloc((size_t)N_NODES * 4);
  int*   csr    = (int*)alloc((size_t)E_TOT * 4);
  int*   bsum   = (int*)alloc(256 * 4);
  float* aS     = (float*)alloc((size_t)N_NODES * 4 * 4);
  float* aD     = (float*)alloc((size_t)N_NODES * 4 * 4);
  float* h3     = (float*)alloc((size_t)N_NODES * 2 * 4);
  float* a3s    = (float*)alloc((size_t)N_NODES * 4);
  float* a3d    = (float*)alloc((size_t)N_NODES * 4);
  unsigned short* W1t = (unsigned short*)alloc((size_t)256 * 128 * 2);
  unsigned short* W2t = (unsigned short*)alloc((size_t)128 * 256 * 2);
  unsigned short* hq1 = (unsigned short*)alloc((size_t)N_NODES * 256 * 2);  // gemm1 out
  unsigned short* hBq = (unsigned short*)alloc((size_t)N_NODES * 256 * 2);  // aggr1 out
  unsigned short* hq2 = (unsigned short*)alloc((size_t)N_NODES * 128 * 2);  // gemm2 out

  // ---- W conversions (tiny)
  k_convW<<<(CW2 + 255) / 256, 256, 0, stream>>>(W1, W2, W1t, W2t);

  // ---- cooperative one-shot CSR build
  {
    const int* ei_a = ei;
    void* args[] = {(void*)&ei_a, (void*)&cnt, (void*)&rowptr,
                    (void*)&cursor, (void*)&csr, (void*)&bsum};
    hipLaunchCooperativeKernel((void*)k_csr, dim3(1024), dim3(256), args, 0, stream);
  }

  const int GB = (N_NODES + 127) / 128;  // 391

  // ---- layer 1: 128 -> 4x64, concat, ELU (A = fp32 x, in-register convert)
  k_gemm_mfma<128, 4, 128, true><<<GB, 512, 0, stream>>>(
      x, W1t, as1, ad1, hq1, aS, aD, N_NODES);
  k_aggr<4, true, true, false><<<(N_NODES + 3) / 4, 256, 0, stream>>>(
      rowptr, csr, hq1, aS, aD, b1, hBq,
      nullptr, nullptr, nullptr, nullptr, nullptr, nullptr);

  // ---- layer 2: 256 -> 2x64, concat, ELU; epilogue fuses layer-3 projection
  k_gemm_mfma<256, 2, 128, false><<<GB, 512, 0, stream>>>(
      hBq, W2t, as2, ad2, hq2, aS, aD, N_NODES);
  k_aggr<2, true, false, true><<<(N_NODES + 3) / 4, 256, 0, stream>>>(
      rowptr, csr, hq2, aS, aD, b2, nullptr,
      W3, as3, ad3, h3, a3s, a3d);

  // ---- layer 3 aggregate + log_softmax
  k_aggr3<<<(N_NODES + 255) / 256, 256, 0, stream>>>(rowptr, csr, h3, a3s, a3d, b3, out);
}

// Round 11
// 255.176 us; speedup vs baseline: 2.8360x; 2.8360x over previous
//
#include <hip/hip_runtime.h>

#define N_NODES 50000
#define N_EDGES 800000
#define E_TOT   (N_EDGES + N_NODES)   // 850000, self-loops appended at end
#define SCAN_B  ((N_NODES + 255) / 256)  // 196

using bfrag = __attribute__((ext_vector_type(8))) short;
using f32x4 = __attribute__((ext_vector_type(4))) float;

// ---------------------------------------------------------------- bf16 helpers
__device__ __forceinline__ float bflo(unsigned int p) {
  union { unsigned int u; float f; } v; v.u = p << 16; return v.f;
}
__device__ __forceinline__ float bfhi(unsigned int p) {
  union { unsigned int u; float f; } v; v.u = p & 0xFFFF0000u; return v.f;
}
__device__ __forceinline__ unsigned short f2bf(float f) {
  union { float f; unsigned int u; } v; v.f = f;
  unsigned int r = v.u + 0x7FFFu + ((v.u >> 16) & 1u);
  return (unsigned short)(r >> 16);
}
__device__ __forceinline__ void unpack8(uint4 u, float* hv) {
  hv[0] = bflo(u.x); hv[1] = bfhi(u.x);
  hv[2] = bflo(u.y); hv[3] = bfhi(u.y);
  hv[4] = bflo(u.z); hv[5] = bfhi(u.z);
  hv[6] = bflo(u.w); hv[7] = bfhi(u.w);
}

// ------------------------------------------------- W-only conversions (tiny)
#define CW1 (128 * 256)
#define CW2 (CW1 + 256 * 128)
__global__ void k_convW(const float* __restrict__ W1, const float* __restrict__ W2,
                        unsigned short* __restrict__ W1t, unsigned short* __restrict__ W2t) {
  int i = blockIdx.x * blockDim.x + threadIdx.x;
  if (i < CW1) {
    int k = i >> 8, n = i & 255;
    W1t[n * 128 + k] = f2bf(W1[i]);
  } else if (i < CW2) {
    int j = i - CW1;
    int k = j >> 7, n = j & 127;
    W2t[n * 256 + k] = f2bf(W2[j]);
  }
}

// ---------------------------------------------------------------- CSR build
__global__ void k_hist(const int* __restrict__ ei, int* __restrict__ cnt) {
  int e = blockIdx.x * blockDim.x + threadIdx.x;
  if (e >= E_TOT) return;
  int d = (e < N_EDGES) ? ei[N_EDGES + e] : (e - N_EDGES);
  atomicAdd(&cnt[d], 1);
}

__global__ void k_bsum(const int* __restrict__ cnt, int* __restrict__ bsum) {
  int t = threadIdx.x;
  int i = blockIdx.x * 256 + t;
  int v = (i < N_NODES) ? cnt[i] : 0;
  #pragma unroll
  for (int off = 32; off; off >>= 1) v += __shfl_down(v, off);
  __shared__ int ws[4];
  if ((t & 63) == 0) ws[t >> 6] = v;
  __syncthreads();
  if (t == 0) bsum[blockIdx.x] = ws[0] + ws[1] + ws[2] + ws[3];
}

__global__ void k_bscan(const int* __restrict__ bsum, int* __restrict__ boff) {
  __shared__ int s[256];
  int t = threadIdx.x;
  int v = (t < SCAN_B) ? bsum[t] : 0;
  s[t] = v;
  __syncthreads();
  for (int off = 1; off < 256; off <<= 1) {
    int x = (t >= off) ? s[t - off] : 0;
    __syncthreads();
    s[t] += x;
    __syncthreads();
  }
  boff[t] = s[t] - v;  // exclusive
}

__global__ void k_rowptr(const int* __restrict__ cnt, const int* __restrict__ boff,
                         int* __restrict__ rowptr, int* __restrict__ cursor) {
  __shared__ int s[256];
  int t = threadIdx.x;
  int i = blockIdx.x * 256 + t;
  int v = (i < N_NODES) ? cnt[i] : 0;
  s[t] = v;
  __syncthreads();
  for (int off = 1; off < 256; off <<= 1) {
    int x = (t >= off) ? s[t - off] : 0;
    __syncthreads();
    s[t] += x;
    __syncthreads();
  }
  int excl = boff[blockIdx.x] + s[t] - v;
  if (i < N_NODES) { rowptr[i] = excl; cursor[i] = excl; }
  if (i == N_NODES - 1) rowptr[N_NODES] = excl + v;
}

__global__ void k_scatter(const int* __restrict__ ei, int* __restrict__ cursor,
                          int* __restrict__ csr) {
  int e = blockIdx.x * blockDim.x + threadIdx.x;
  if (e >= E_TOT) return;
  int s, d;
  if (e < N_EDGES) { s = ei[e]; d = ei[N_EDGES + e]; }
  else             { s = d = e - N_EDGES; }
  int pos = atomicAdd(&cursor[d], 1);
  csr[pos] = s;
}

// ------------------------------------------- MFMA bf16 GEMM + fused epilogue
// ROWS rows per block, all H heads full-width. A32: A is fp32, convert
// in-register during the A-fragment load (kills the x->bf16 pre-pass).
template <int KD, int H, int ROWS, bool A32>
__global__ __launch_bounds__(ROWS * 4) void k_gemm_mfma(
    const void* __restrict__ Aq, const unsigned short* __restrict__ Wt,
    const float* __restrict__ atts, const float* __restrict__ attd,
    unsigned short* __restrict__ hq, float* __restrict__ aS,
    float* __restrict__ aD, int M) {
  constexpr int NN = H * 64;
  constexpr int KH = KD / 2;              // K per half
  constexpr int GR = KH / 8;              // 16B granules per col per half
  constexpr int T  = ROWS * 4;            // threads
  __shared__ unsigned short Bts[NN * KH]; // 32 KB
  int t = threadIdx.x;
  int lane = t & 63;
  int w = t >> 6;
  int arow = blockIdx.x * ROWS + w * 16 + (lane & 15);
  int arow_c = arow < M ? arow : M - 1;
  const unsigned short* ArowB = (const unsigned short*)Aq + (size_t)arow_c * KD;
  const float*          ArowF = (const float*)Aq + (size_t)arow_c * KD;

  f32x4 acc[NN / 16] = {};
  #pragma unroll
  for (int half = 0; half < 2; ++half) {
    if (half) __syncthreads();
    #pragma unroll
    for (int c = 0; c < NN * KH / 8 / T; ++c) {
      int chunk = t + c * T;
      int col = chunk / GR;
      int kc  = chunk % GR;
      uint4 v = *(const uint4*)&Wt[(size_t)col * KD + half * KH + kc * 8];
      int swz = kc ^ (col & 7);
      *(uint4*)&Bts[col * KH + swz * 8] = v;
    }
    __syncthreads();
    for (int k0 = 0; k0 < KH; k0 += 32) {
      int gl = (k0 >> 3) + (lane >> 4);
      bfrag a;
      if constexpr (A32) {
        const float* Ap = ArowF + half * KH + gl * 8;
        float4 v0 = *(const float4*)Ap;
        float4 v1 = *(const float4*)(Ap + 4);
        a[0] = (short)f2bf(v0.x); a[1] = (short)f2bf(v0.y);
        a[2] = (short)f2bf(v0.z); a[3] = (short)f2bf(v0.w);
        a[4] = (short)f2bf(v1.x); a[5] = (short)f2bf(v1.y);
        a[6] = (short)f2bf(v1.z); a[7] = (short)f2bf(v1.w);
      } else {
        a = *(const bfrag*)&ArowB[half * KH + gl * 8];
      }
      #pragma unroll
      for (int cf = 0; cf < NN / 16; ++cf) {
        int col = cf * 16 + (lane & 15);
        int gs = gl ^ (col & 7);
        bfrag b = *(const bfrag*)&Bts[col * KH + gs * 8];
        acc[cf] = __builtin_amdgcn_mfma_f32_16x16x32_bf16(a, b, acc[cf], 0, 0, 0);
      }
    }
  }

  float ws_[NN / 16], wd_[NN / 16];
  #pragma unroll
  for (int cf = 0; cf < NN / 16; ++cf) {
    ws_[cf] = atts[cf * 16 + (lane & 15)];
    wd_[cf] = attd[cf * 16 + (lane & 15)];
  }
  int orow0 = blockIdx.x * ROWS + w * 16 + (lane >> 4) * 4;
  #pragma unroll
  for (int hh = 0; hh < H; ++hh) {
    float ps[4] = {}, pd[4] = {};
    #pragma unroll
    for (int c4 = 0; c4 < 4; ++c4) {
      int cf = hh * 4 + c4;
      #pragma unroll
      for (int i = 0; i < 4; ++i) {
        ps[i] += acc[cf][i] * ws_[cf];
        pd[i] += acc[cf][i] * wd_[cf];
      }
    }
    #pragma unroll
    for (int off = 1; off < 16; off <<= 1)
      #pragma unroll
      for (int i = 0; i < 4; ++i) {
        ps[i] += __shfl_xor(ps[i], off);
        pd[i] += __shfl_xor(pd[i], off);
      }
    if ((lane & 15) == 0)
      #pragma unroll
      for (int i = 0; i < 4; ++i) {
        int r = orow0 + i;
        if (r < M) {
          aS[(size_t)r * H + hh] = ps[i];
          aD[(size_t)r * H + hh] = pd[i];
        }
      }
  }
  #pragma unroll
  for (int i = 0; i < 4; ++i) {
    int r = orow0 + i;
    if (r < M)
      #pragma unroll
      for (int cf = 0; cf < NN / 16; ++cf)
        hq[(size_t)r * NN + cf * 16 + (lane & 15)] = f2bf(acc[cf][i]);
  }
}

// -------------- edge-softmax + aggregate, NO-MAX softmax. Phase 0 stages
// j + w=exp(leaky(aS+aD)), per-lane denom. Phase 1: predication-free 2D
// gather. PROJ3 fuses the layer-3 projection into the epilogue.
template <int H, bool ELU, bool OBF, bool PROJ3>
__global__ __launch_bounds__(256) void k_aggr(
    const int* __restrict__ rowptr, const int* __restrict__ csr,
    const unsigned short* __restrict__ hq,
    const float* __restrict__ aS, const float* __restrict__ aD,
    const float* __restrict__ bias, void* __restrict__ outv,
    const float* __restrict__ W3, const float* __restrict__ s3,
    const float* __restrict__ d3, float* __restrict__ h3o,
    float* __restrict__ a3so, float* __restrict__ a3do) {
  constexpr int CAP = 64;
  constexpr int C = H * 64;
  constexpr int EPW = 512 / C;      // edges per wave instr: H=4 -> 2, H=2 -> 4
  constexpr int LPE = 64 / EPW;     // lanes per edge
  __shared__ int   jls[4][CAP];
  __shared__ float wls[4][CAP * H];
  int n    = (int)((blockIdx.x * (size_t)blockDim.x + threadIdx.x) >> 6);
  int lane = threadIdx.x & 63;
  int wsl  = threadIdx.x >> 6;
  if (n >= N_NODES) return;
  int* jl  = jls[wsl];
  float* wl = wls[wsl];
  int cg  = lane & (LPE - 1);       // channel group: channels cg*8 .. cg*8+7
  int sub = lane / LPE;             // which edge of the EPW-pack
  int hlc = cg >> 3;                // head owning this lane's channels

  float ad[H];
  #pragma unroll
  for (int h = 0; h < H; ++h) ad[h] = aD[(size_t)n * H + h];

  int lo = rowptr[n], deg = rowptr[n + 1] - lo;
  float sl[H] = {};                 // per-lane partial denominators
  float acc8[8] = {};

  for (int c0 = 0; c0 < deg; c0 += CAP) {
    int cl = deg - c0; if (cl > CAP) cl = CAP;
    int clp = (cl + EPW - 1) & ~(EPW - 1);   // pad to EPW multiple
    // ---- phase 0: stage j + w = exp(leaky(aS+aD)); accumulate denom
    for (int kk = lane; kk < clp; kk += 64) {
      bool v = kk < cl;
      int j = v ? csr[lo + c0 + kk] : n;     // pad: self (valid row), w=0
      jl[kk] = j;
      float e[H];
      if constexpr (H == 4) {
        float4 a4 = *(const float4*)&aS[(size_t)j * 4];
        e[0] = a4.x; e[1] = a4.y; e[2] = a4.z; e[3] = a4.w;
      } else {
        float2 a2 = *(const float2*)&aS[(size_t)j * 2];
        e[0] = a2.x; e[1] = a2.y;
      }
      #pragma unroll
      for (int h = 0; h < H; ++h) {
        float ev = e[h] + ad[h];
        ev = ev > 0.f ? ev : 0.2f * ev;
        float w = v ? __expf(ev) : 0.f;
        sl[h] += w;
        e[h] = w;
      }
      if constexpr (H == 4)
        *(float4*)&wl[kk * 4] = make_float4(e[0], e[1], e[2], e[3]);
      else
        *(float2*)&wl[kk * 2] = make_float2(e[0], e[1]);
    }
    __builtin_amdgcn_wave_barrier();
    // ---- phase 1: predication-free 2D gather-accumulate
    #pragma unroll 4
    for (int k = 0; k < clp; k += EPW) {
      int idx = k + sub;
      int j = jl[idx];
      float wgt = wl[idx * H + hlc];
      uint4 u = *(const uint4*)&hq[(size_t)j * C + cg * 8];
      float hv[8];
      unpack8(u, hv);
      #pragma unroll
      for (int i = 0; i < 8; ++i) acc8[i] += wgt * hv[i];
    }
    __builtin_amdgcn_wave_barrier();
  }

  // single denominator reduction per node (all lanes end with totals)
  #pragma unroll
  for (int off = 1; off < 64; off <<= 1)
    #pragma unroll
    for (int h = 0; h < H; ++h) sl[h] += __shfl_xor(sl[h], off);

  // fold the EPW edge-subgroups: all lanes end with folded totals
  #pragma unroll
  for (int i = 0; i < 8; ++i) {
    if constexpr (EPW == 4) acc8[i] += __shfl_xor(acc8[i], 16);
    acc8[i] += __shfl_xor(acc8[i], 32);
  }

  float inv = 1.f / sl[hlc];
  float o[8];
  #pragma unroll
  for (int i = 0; i < 8; ++i) {
    float v = acc8[i] * inv + bias[cg * 8 + i];
    if (ELU) v = v > 0.f ? v : __expf(v) - 1.f;
    o[i] = v;
  }

  if constexpr (PROJ3) {
    // fused layer-3 projection: h3 = o . W3 (128x2), a3s/a3d from h3
    float a0 = 0.f, a1 = 0.f;
    #pragma unroll
    for (int i = 0; i < 8; ++i) {
      int c = cg * 8 + i;
      a0 += o[i] * W3[c * 2 + 0];
      a1 += o[i] * W3[c * 2 + 1];
    }
    #pragma unroll
    for (int off = 1; off < 16; off <<= 1) {
      a0 += __shfl_xor(a0, off);
      a1 += __shfl_xor(a1, off);
    }
    if (lane == 0) {
      h3o[(size_t)n * 2]     = a0;
      h3o[(size_t)n * 2 + 1] = a1;
      a3so[n] = a0 * s3[0] + a1 * s3[1];
      a3do[n] = a0 * d3[0] + a1 * d3[1];
    }
  } else if (sub == 0) {
    size_t idx = (size_t)n * C + cg * 8;
    if constexpr (OBF) {
      unsigned short* outp = (unsigned short*)outv;
      uint4 r;
      r.x = (unsigned int)f2bf(o[0]) | ((unsigned int)f2bf(o[1]) << 16);
      r.y = (unsigned int)f2bf(o[2]) | ((unsigned int)f2bf(o[3]) << 16);
      r.z = (unsigned int)f2bf(o[4]) | ((unsigned int)f2bf(o[5]) << 16);
      r.w = (unsigned int)f2bf(o[6]) | ((unsigned int)f2bf(o[7]) << 16);
      *(uint4*)&outp[idx] = r;
    } else {
      float* outp = (float*)outv;
      *(float4*)&outp[idx]     = make_float4(o[0], o[1], o[2], o[3]);
      *(float4*)&outp[idx + 4] = make_float4(o[4], o[5], o[6], o[7]);
    }
  }
}

// --------------------------------------------------------- layer-3 aggregate
__global__ void k_aggr3(const int* __restrict__ rowptr, const int* __restrict__ csr,
                        const float* __restrict__ h3, const float* __restrict__ a3s,
                        const float* __restrict__ a3d, const float* __restrict__ b3,
                        float* __restrict__ out) {
  int n = blockIdx.x * blockDim.x + threadIdx.x;
  if (n >= N_NODES) return;
  float adv = a3d[n];
  float s = 0.f, acc0 = 0.f, acc1 = 0.f;
  int lo = rowptr[n], hi = rowptr[n + 1];
  for (int k = lo; k < hi; ++k) {
    int j = csr[k];
    float e = a3s[j] + adv;
    e = e > 0.f ? e : 0.2f * e;
    float w = __expf(e);           // no-max softmax (logits small)
    float2 h = *(const float2*)&h3[(size_t)j * 2];
    s += w; acc0 += w * h.x; acc1 += w * h.y;
  }
  float o0 = acc0 / s + b3[0];
  float o1 = acc1 / s + b3[1];
  float mx = fmaxf(o0, o1);
  float l  = logf(__expf(o0 - mx) + __expf(o1 - mx));
  out[(size_t)n * 2]     = o0 - mx - l;
  out[(size_t)n * 2 + 1] = o1 - mx - l;
}

// ---------------------------------------------------------------- launcher
extern "C" void kernel_launch(void* const* d_in, const int* in_sizes, int n_in,
                              void* d_out, int out_size, void* d_ws, size_t ws_size,
                              hipStream_t stream) {
  const float* x   = (const float*)d_in[0];
  const int*   ei  = (const int*)d_in[1];
  const float* W1  = (const float*)d_in[2];
  const float* as1 = (const float*)d_in[3];
  const float* ad1 = (const float*)d_in[4];
  const float* b1  = (const float*)d_in[5];
  const float* W2  = (const float*)d_in[6];
  const float* as2 = (const float*)d_in[7];
  const float* ad2 = (const float*)d_in[8];
  const float* b2  = (const float*)d_in[9];
  const float* W3  = (const float*)d_in[10];
  const float* as3 = (const float*)d_in[11];
  const float* ad3 = (const float*)d_in[12];
  const float* b3  = (const float*)d_in[13];
  float* out = (float*)d_out;

  char* p = (char*)d_ws;
  auto alloc = [&](size_t bytes) -> char* {
    char* r = p; p += (bytes + 255) & ~(size_t)255; return r;
  };
  int*   cnt    = (int*)alloc((size_t)N_NODES * 4);
  int*   rowptr = (int*)alloc((size_t)(N_NODES + 1) * 4);
  int*   cursor = (int*)alloc((size_t)N_NODES * 4);
  int*   csr    = (int*)alloc((size_t)E_TOT * 4);
  int*   bsum   = (int*)alloc(256 * 4);
  int*   boff   = (int*)alloc(257 * 4);
  float* aS     = (float*)alloc((size_t)N_NODES * 4 * 4);
  float* aD     = (float*)alloc((size_t)N_NODES * 4 * 4);
  float* h3     = (float*)alloc((size_t)N_NODES * 2 * 4);
  float* a3s    = (float*)alloc((size_t)N_NODES * 4);
  float* a3d    = (float*)alloc((size_t)N_NODES * 4);
  unsigned short* W1t = (unsigned short*)alloc((size_t)256 * 128 * 2);
  unsigned short* W2t = (unsigned short*)alloc((size_t)128 * 256 * 2);
  unsigned short* hq1 = (unsigned short*)alloc((size_t)N_NODES * 256 * 2);  // gemm1 out
  unsigned short* hBq = (unsigned short*)alloc((size_t)N_NODES * 256 * 2);  // aggr1 out
  unsigned short* hq2 = (unsigned short*)alloc((size_t)N_NODES * 128 * 2);  // gemm2 out

  // ---- W conversions (tiny)
  k_convW<<<(CW2 + 255) / 256, 256, 0, stream>>>(W1, W2, W1t, W2t);

  // ---- CSR build (separate kernels; coop grid.sync costs ~100us each on 8-XCD)
  hipMemsetAsync(cnt, 0, (size_t)N_NODES * 4, stream);
  k_hist<<<(E_TOT + 255) / 256, 256, 0, stream>>>(ei, cnt);
  k_bsum<<<SCAN_B, 256, 0, stream>>>(cnt, bsum);
  k_bscan<<<1, 256, 0, stream>>>(bsum, boff);
  k_rowptr<<<SCAN_B, 256, 0, stream>>>(cnt, boff, rowptr, cursor);
  k_scatter<<<(E_TOT + 255) / 256, 256, 0, stream>>>(ei, cursor, csr);

  const int GB = (N_NODES + 127) / 128;  // 391

  // ---- layer 1: 128 -> 4x64, concat, ELU (A = fp32 x, in-register convert)
  k_gemm_mfma<128, 4, 128, true><<<GB, 512, 0, stream>>>(
      x, W1t, as1, ad1, hq1, aS, aD, N_NODES);
  k_aggr<4, true, true, false><<<(N_NODES + 3) / 4, 256, 0, stream>>>(
      rowptr, csr, hq1, aS, aD, b1, hBq,
      nullptr, nullptr, nullptr, nullptr, nullptr, nullptr);

  // ---- layer 2: 256 -> 2x64, concat, ELU; epilogue fuses layer-3 projection
  k_gemm_mfma<256, 2, 128, false><<<GB, 512, 0, stream>>>(
      hBq, W2t, as2, ad2, hq2, aS, aD, N_NODES);
  k_aggr<2, true, false, true><<<(N_NODES + 3) / 4, 256, 0, stream>>>(
      rowptr, csr, hq2, aS, aD, b2, nullptr,
      W3, as3, ad3, h3, a3s, a3d);

  // ---- layer 3 aggregate + log_softmax
  k_aggr3<<<(N_NODES + 255) / 256, 256, 0, stream>>>(rowptr, csr, h3, a3s, a3d, b3, out);
}

// Round 12
// 253.256 us; speedup vs baseline: 2.8574x; 1.0076x over previous
//
#include <hip/hip_runtime.h>

#define N_NODES 50000
#define N_EDGES 800000
#define E_TOT   (N_EDGES + N_NODES)   // 850000, self-loops appended at end
#define SCAN_B  ((N_NODES + 255) / 256)  // 196

using bfrag = __attribute__((ext_vector_type(8))) short;
using f32x4 = __attribute__((ext_vector_type(4))) float;

// ---------------------------------------------------------------- bf16 helpers
__device__ __forceinline__ float bflo(unsigned int p) {
  union { unsigned int u; float f; } v; v.u = p << 16; return v.f;
}
__device__ __forceinline__ float bfhi(unsigned int p) {
  union { unsigned int u; float f; } v; v.u = p & 0xFFFF0000u; return v.f;
}
__device__ __forceinline__ unsigned short f2bf(float f) {
  union { float f; unsigned int u; } v; v.f = f;
  unsigned int r = v.u + 0x7FFFu + ((v.u >> 16) & 1u);
  return (unsigned short)(r >> 16);
}
__device__ __forceinline__ void unpack8(uint4 u, float* hv) {
  hv[0] = bflo(u.x); hv[1] = bfhi(u.x);
  hv[2] = bflo(u.y); hv[3] = bfhi(u.y);
  hv[4] = bflo(u.z); hv[5] = bfhi(u.z);
  hv[6] = bflo(u.w); hv[7] = bfhi(u.w);
}

// --------------------- W conversions + cnt zeroing (grid covers both ranges)
#define CW1 (128 * 256)
#define CW2 (CW1 + 256 * 128)
__global__ void k_convW(const float* __restrict__ W1, const float* __restrict__ W2,
                        unsigned short* __restrict__ W1t, unsigned short* __restrict__ W2t,
                        int* __restrict__ cnt) {
  int i = blockIdx.x * blockDim.x + threadIdx.x;
  if (i < N_NODES) cnt[i] = 0;              // fold the memset dispatch in here
  if (i < CW1) {
    int k = i >> 8, n = i & 255;
    W1t[n * 128 + k] = f2bf(W1[i]);
  } else if (i < CW2) {
    int j = i - CW1;
    int k = j >> 7, n = j & 127;
    W2t[n * 256 + k] = f2bf(W2[j]);
  }
}

// ---------------------------------------------------------------- CSR build
__global__ void k_hist(const int* __restrict__ ei, int* __restrict__ cnt) {
  int e = blockIdx.x * blockDim.x + threadIdx.x;
  if (e >= E_TOT) return;
  int d = (e < N_EDGES) ? ei[N_EDGES + e] : (e - N_EDGES);
  atomicAdd(&cnt[d], 1);
}

__global__ void k_bsum(const int* __restrict__ cnt, int* __restrict__ bsum) {
  int t = threadIdx.x;
  int i = blockIdx.x * 256 + t;
  int v = (i < N_NODES) ? cnt[i] : 0;
  #pragma unroll
  for (int off = 32; off; off >>= 1) v += __shfl_down(v, off);
  __shared__ int ws[4];
  if ((t & 63) == 0) ws[t >> 6] = v;
  __syncthreads();
  if (t == 0) bsum[blockIdx.x] = ws[0] + ws[1] + ws[2] + ws[3];
}

__global__ void k_bscan(const int* __restrict__ bsum, int* __restrict__ boff) {
  __shared__ int s[256];
  int t = threadIdx.x;
  int v = (t < SCAN_B) ? bsum[t] : 0;
  s[t] = v;
  __syncthreads();
  for (int off = 1; off < 256; off <<= 1) {
    int x = (t >= off) ? s[t - off] : 0;
    __syncthreads();
    s[t] += x;
    __syncthreads();
  }
  boff[t] = s[t] - v;  // exclusive
}

__global__ void k_rowptr(const int* __restrict__ cnt, const int* __restrict__ boff,
                         int* __restrict__ rowptr, int* __restrict__ cursor) {
  __shared__ int s[256];
  int t = threadIdx.x;
  int i = blockIdx.x * 256 + t;
  int v = (i < N_NODES) ? cnt[i] : 0;
  s[t] = v;
  __syncthreads();
  for (int off = 1; off < 256; off <<= 1) {
    int x = (t >= off) ? s[t - off] : 0;
    __syncthreads();
    s[t] += x;
    __syncthreads();
  }
  int excl = boff[blockIdx.x] + s[t] - v;
  if (i < N_NODES) { rowptr[i] = excl; cursor[i] = excl; }
  if (i == N_NODES - 1) rowptr[N_NODES] = excl + v;
}

__global__ void k_scatter(const int* __restrict__ ei, int* __restrict__ cursor,
                          int* __restrict__ csr) {
  int e = blockIdx.x * blockDim.x + threadIdx.x;
  if (e >= E_TOT) return;
  int s, d;
  if (e < N_EDGES) { s = ei[e]; d = ei[N_EDGES + e]; }
  else             { s = d = e - N_EDGES; }
  int pos = atomicAdd(&cursor[d], 1);
  csr[pos] = s;
}

// ------------------------------------------- MFMA bf16 GEMM + fused epilogue
// ROWS rows per block, all H heads full-width. A32: A is fp32, convert
// in-register during the A-fragment load (kills the x->bf16 pre-pass).
template <int KD, int H, int ROWS, bool A32>
__global__ __launch_bounds__(ROWS * 4) void k_gemm_mfma(
    const void* __restrict__ Aq, const unsigned short* __restrict__ Wt,
    const float* __restrict__ atts, const float* __restrict__ attd,
    unsigned short* __restrict__ hq, float* __restrict__ aS,
    float* __restrict__ aD, int M) {
  constexpr int NN = H * 64;
  constexpr int KH = KD / 2;              // K per half
  constexpr int GR = KH / 8;              // 16B granules per col per half
  constexpr int T  = ROWS * 4;            // threads
  __shared__ unsigned short Bts[NN * KH]; // 32 KB
  int t = threadIdx.x;
  int lane = t & 63;
  int w = t >> 6;
  int arow = blockIdx.x * ROWS + w * 16 + (lane & 15);
  int arow_c = arow < M ? arow : M - 1;
  const unsigned short* ArowB = (const unsigned short*)Aq + (size_t)arow_c * KD;
  const float*          ArowF = (const float*)Aq + (size_t)arow_c * KD;

  f32x4 acc[NN / 16] = {};
  #pragma unroll
  for (int half = 0; half < 2; ++half) {
    if (half) __syncthreads();
    #pragma unroll
    for (int c = 0; c < NN * KH / 8 / T; ++c) {
      int chunk = t + c * T;
      int col = chunk / GR;
      int kc  = chunk % GR;
      uint4 v = *(const uint4*)&Wt[(size_t)col * KD + half * KH + kc * 8];
      int swz = kc ^ (col & 7);
      *(uint4*)&Bts[col * KH + swz * 8] = v;
    }
    __syncthreads();
    for (int k0 = 0; k0 < KH; k0 += 32) {
      int gl = (k0 >> 3) + (lane >> 4);
      bfrag a;
      if constexpr (A32) {
        const float* Ap = ArowF + half * KH + gl * 8;
        float4 v0 = *(const float4*)Ap;
        float4 v1 = *(const float4*)(Ap + 4);
        a[0] = (short)f2bf(v0.x); a[1] = (short)f2bf(v0.y);
        a[2] = (short)f2bf(v0.z); a[3] = (short)f2bf(v0.w);
        a[4] = (short)f2bf(v1.x); a[5] = (short)f2bf(v1.y);
        a[6] = (short)f2bf(v1.z); a[7] = (short)f2bf(v1.w);
      } else {
        a = *(const bfrag*)&ArowB[half * KH + gl * 8];
      }
      #pragma unroll
      for (int cf = 0; cf < NN / 16; ++cf) {
        int col = cf * 16 + (lane & 15);
        int gs = gl ^ (col & 7);
        bfrag b = *(const bfrag*)&Bts[col * KH + gs * 8];
        acc[cf] = __builtin_amdgcn_mfma_f32_16x16x32_bf16(a, b, acc[cf], 0, 0, 0);
      }
    }
  }

  float ws_[NN / 16], wd_[NN / 16];
  #pragma unroll
  for (int cf = 0; cf < NN / 16; ++cf) {
    ws_[cf] = atts[cf * 16 + (lane & 15)];
    wd_[cf] = attd[cf * 16 + (lane & 15)];
  }
  int orow0 = blockIdx.x * ROWS + w * 16 + (lane >> 4) * 4;
  #pragma unroll
  for (int hh = 0; hh < H; ++hh) {
    float ps[4] = {}, pd[4] = {};
    #pragma unroll
    for (int c4 = 0; c4 < 4; ++c4) {
      int cf = hh * 4 + c4;
      #pragma unroll
      for (int i = 0; i < 4; ++i) {
        ps[i] += acc[cf][i] * ws_[cf];
        pd[i] += acc[cf][i] * wd_[cf];
      }
    }
    #pragma unroll
    for (int off = 1; off < 16; off <<= 1)
      #pragma unroll
      for (int i = 0; i < 4; ++i) {
        ps[i] += __shfl_xor(ps[i], off);
        pd[i] += __shfl_xor(pd[i], off);
      }
    if ((lane & 15) == 0)
      #pragma unroll
      for (int i = 0; i < 4; ++i) {
        int r = orow0 + i;
        if (r < M) {
          aS[(size_t)r * H + hh] = ps[i];
          aD[(size_t)r * H + hh] = pd[i];
        }
      }
  }
  #pragma unroll
  for (int i = 0; i < 4; ++i) {
    int r = orow0 + i;
    if (r < M)
      #pragma unroll
      for (int cf = 0; cf < NN / 16; ++cf)
        hq[(size_t)r * NN + cf * 16 + (lane & 15)] = f2bf(acc[cf][i]);
  }
}

// -------------- edge-softmax + aggregate, NO-MAX softmax. Phase 0 stages
// j + w=exp(leaky(aS+aD)), per-lane denom. Phase 1: predication-free 2D
// gather. PROJ3 fuses the layer-3 projection into the epilogue.
template <int H, bool ELU, bool OBF, bool PROJ3>
__global__ __launch_bounds__(256) void k_aggr(
    const int* __restrict__ rowptr, const int* __restrict__ csr,
    const unsigned short* __restrict__ hq,
    const float* __restrict__ aS, const float* __restrict__ aD,
    const float* __restrict__ bias, void* __restrict__ outv,
    const float* __restrict__ W3, const float* __restrict__ s3,
    const float* __restrict__ d3, float* __restrict__ h3o,
    float* __restrict__ a3so, float* __restrict__ a3do) {
  constexpr int CAP = 64;
  constexpr int C = H * 64;
  constexpr int EPW = 512 / C;      // edges per wave instr: H=4 -> 2, H=2 -> 4
  constexpr int LPE = 64 / EPW;     // lanes per edge
  __shared__ int   jls[4][CAP];
  __shared__ float wls[4][CAP * H];
  int n    = (int)((blockIdx.x * (size_t)blockDim.x + threadIdx.x) >> 6);
  int lane = threadIdx.x & 63;
  int wsl  = threadIdx.x >> 6;
  if (n >= N_NODES) return;
  int* jl  = jls[wsl];
  float* wl = wls[wsl];
  int cg  = lane & (LPE - 1);       // channel group: channels cg*8 .. cg*8+7
  int sub = lane / LPE;             // which edge of the EPW-pack
  int hlc = cg >> 3;                // head owning this lane's channels

  float ad[H];
  #pragma unroll
  for (int h = 0; h < H; ++h) ad[h] = aD[(size_t)n * H + h];

  int lo = rowptr[n], deg = rowptr[n + 1] - lo;
  float sl[H] = {};                 // per-lane partial denominators
  float acc8[8] = {};

  for (int c0 = 0; c0 < deg; c0 += CAP) {
    int cl = deg - c0; if (cl > CAP) cl = CAP;
    int clp = (cl + EPW - 1) & ~(EPW - 1);   // pad to EPW multiple
    // ---- phase 0: stage j + w = exp(leaky(aS+aD)); accumulate denom
    for (int kk = lane; kk < clp; kk += 64) {
      bool v = kk < cl;
      int j = v ? csr[lo + c0 + kk] : n;     // pad: self (valid row), w=0
      jl[kk] = j;
      float e[H];
      if constexpr (H == 4) {
        float4 a4 = *(const float4*)&aS[(size_t)j * 4];
        e[0] = a4.x; e[1] = a4.y; e[2] = a4.z; e[3] = a4.w;
      } else {
        float2 a2 = *(const float2*)&aS[(size_t)j * 2];
        e[0] = a2.x; e[1] = a2.y;
      }
      #pragma unroll
      for (int h = 0; h < H; ++h) {
        float ev = e[h] + ad[h];
        ev = ev > 0.f ? ev : 0.2f * ev;
        float w = v ? __expf(ev) : 0.f;
        sl[h] += w;
        e[h] = w;
      }
      if constexpr (H == 4)
        *(float4*)&wl[kk * 4] = make_float4(e[0], e[1], e[2], e[3]);
      else
        *(float2*)&wl[kk * 2] = make_float2(e[0], e[1]);
    }
    __builtin_amdgcn_wave_barrier();
    // ---- phase 1: predication-free 2D gather-accumulate
    #pragma unroll 4
    for (int k = 0; k < clp; k += EPW) {
      int idx = k + sub;
      int j = jl[idx];
      float wgt = wl[idx * H + hlc];
      uint4 u = *(const uint4*)&hq[(size_t)j * C + cg * 8];
      float hv[8];
      unpack8(u, hv);
      #pragma unroll
      for (int i = 0; i < 8; ++i) acc8[i] += wgt * hv[i];
    }
    __builtin_amdgcn_wave_barrier();
  }

  // single denominator reduction per node (all lanes end with totals)
  #pragma unroll
  for (int off = 1; off < 64; off <<= 1)
    #pragma unroll
    for (int h = 0; h < H; ++h) sl[h] += __shfl_xor(sl[h], off);

  // fold the EPW edge-subgroups: all lanes end with folded totals
  #pragma unroll
  for (int i = 0; i < 8; ++i) {
    if constexpr (EPW == 4) acc8[i] += __shfl_xor(acc8[i], 16);
    acc8[i] += __shfl_xor(acc8[i], 32);
  }

  float inv = 1.f / sl[hlc];
  float o[8];
  #pragma unroll
  for (int i = 0; i < 8; ++i) {
    float v = acc8[i] * inv + bias[cg * 8 + i];
    if (ELU) v = v > 0.f ? v : __expf(v) - 1.f;
    o[i] = v;
  }

  if constexpr (PROJ3) {
    // fused layer-3 projection: h3 = o . W3 (128x2), a3s/a3d from h3
    float a0 = 0.f, a1 = 0.f;
    #pragma unroll
    for (int i = 0; i < 8; ++i) {
      int c = cg * 8 + i;
      a0 += o[i] * W3[c * 2 + 0];
      a1 += o[i] * W3[c * 2 + 1];
    }
    #pragma unroll
    for (int off = 1; off < 16; off <<= 1) {
      a0 += __shfl_xor(a0, off);
      a1 += __shfl_xor(a1, off);
    }
    if (lane == 0) {
      h3o[(size_t)n * 2]     = a0;
      h3o[(size_t)n * 2 + 1] = a1;
      a3so[n] = a0 * s3[0] + a1 * s3[1];
      a3do[n] = a0 * d3[0] + a1 * d3[1];
    }
  } else if (sub == 0) {
    size_t idx = (size_t)n * C + cg * 8;
    if constexpr (OBF) {
      unsigned short* outp = (unsigned short*)outv;
      uint4 r;
      r.x = (unsigned int)f2bf(o[0]) | ((unsigned int)f2bf(o[1]) << 16);
      r.y = (unsigned int)f2bf(o[2]) | ((unsigned int)f2bf(o[3]) << 16);
      r.z = (unsigned int)f2bf(o[4]) | ((unsigned int)f2bf(o[5]) << 16);
      r.w = (unsigned int)f2bf(o[6]) | ((unsigned int)f2bf(o[7]) << 16);
      *(uint4*)&outp[idx] = r;
    } else {
      float* outp = (float*)outv;
      *(float4*)&outp[idx]     = make_float4(o[0], o[1], o[2], o[3]);
      *(float4*)&outp[idx + 4] = make_float4(o[4], o[5], o[6], o[7]);
    }
  }
}

// --------------------------------------------------------- layer-3 aggregate
__global__ void k_aggr3(const int* __restrict__ rowptr, const int* __restrict__ csr,
                        const float* __restrict__ h3, const float* __restrict__ a3s,
                        const float* __restrict__ a3d, const float* __restrict__ b3,
                        float* __restrict__ out) {
  int n = blockIdx.x * blockDim.x + threadIdx.x;
  if (n >= N_NODES) return;
  float adv = a3d[n];
  float s = 0.f, acc0 = 0.f, acc1 = 0.f;
  int lo = rowptr[n], hi = rowptr[n + 1];
  for (int k = lo; k < hi; ++k) {
    int j = csr[k];
    float e = a3s[j] + adv;
    e = e > 0.f ? e : 0.2f * e;
    float w = __expf(e);           // no-max softmax (logits small)
    float2 h = *(const float2*)&h3[(size_t)j * 2];
    s += w; acc0 += w * h.x; acc1 += w * h.y;
  }
  float o0 = acc0 / s + b3[0];
  float o1 = acc1 / s + b3[1];
  float mx = fmaxf(o0, o1);
  float l  = logf(__expf(o0 - mx) + __expf(o1 - mx));
  out[(size_t)n * 2]     = o0 - mx - l;
  out[(size_t)n * 2 + 1] = o1 - mx - l;
}

// ---------------------------------------------------------------- launcher
extern "C" void kernel_launch(void* const* d_in, const int* in_sizes, int n_in,
                              void* d_out, int out_size, void* d_ws, size_t ws_size,
                              hipStream_t stream) {
  const float* x   = (const float*)d_in[0];
  const int*   ei  = (const int*)d_in[1];
  const float* W1  = (const float*)d_in[2];
  const float* as1 = (const float*)d_in[3];
  const float* ad1 = (const float*)d_in[4];
  const float* b1  = (const float*)d_in[5];
  const float* W2  = (const float*)d_in[6];
  const float* as2 = (const float*)d_in[7];
  const float* ad2 = (const float*)d_in[8];
  const float* b2  = (const float*)d_in[9];
  const float* W3  = (const float*)d_in[10];
  const float* as3 = (const float*)d_in[11];
  const float* ad3 = (const float*)d_in[12];
  const float* b3  = (const float*)d_in[13];
  float* out = (float*)d_out;

  char* p = (char*)d_ws;
  auto alloc = [&](size_t bytes) -> char* {
    char* r = p; p += (bytes + 255) & ~(size_t)255; return r;
  };
  int*   cnt    = (int*)alloc((size_t)N_NODES * 4);
  int*   rowptr = (int*)alloc((size_t)(N_NODES + 1) * 4);
  int*   cursor = (int*)alloc((size_t)N_NODES * 4);
  int*   csr    = (int*)alloc((size_t)E_TOT * 4);
  int*   bsum   = (int*)alloc(256 * 4);
  int*   boff   = (int*)alloc(257 * 4);
  float* aS     = (float*)alloc((size_t)N_NODES * 4 * 4);
  float* aD     = (float*)alloc((size_t)N_NODES * 4 * 4);
  float* h3     = (float*)alloc((size_t)N_NODES * 2 * 4);
  float* a3s    = (float*)alloc((size_t)N_NODES * 4);
  float* a3d    = (float*)alloc((size_t)N_NODES * 4);
  unsigned short* W1t = (unsigned short*)alloc((size_t)256 * 128 * 2);
  unsigned short* W2t = (unsigned short*)alloc((size_t)128 * 256 * 2);
  unsigned short* hq1 = (unsigned short*)alloc((size_t)N_NODES * 256 * 2);  // gemm1 out
  unsigned short* hBq = (unsigned short*)alloc((size_t)N_NODES * 256 * 2);  // aggr1 out
  unsigned short* hq2 = (unsigned short*)alloc((size_t)N_NODES * 128 * 2);  // gemm2 out

  // ---- W conversions + cnt zeroing (one dispatch)
  k_convW<<<(CW2 + 255) / 256, 256, 0, stream>>>(W1, W2, W1t, W2t, cnt);

  // ---- CSR build (separate kernels; coop grid.sync costs ~100us each on 8-XCD)
  k_hist<<<(E_TOT + 255) / 256, 256, 0, stream>>>(ei, cnt);
  k_bsum<<<SCAN_B, 256, 0, stream>>>(cnt, bsum);
  k_bscan<<<1, 256, 0, stream>>>(bsum, boff);
  k_rowptr<<<SCAN_B, 256, 0, stream>>>(cnt, boff, rowptr, cursor);
  k_scatter<<<(E_TOT + 255) / 256, 256, 0, stream>>>(ei, cursor, csr);

  const int GB = (N_NODES + 127) / 128;  // 391

  // ---- layer 1: 128 -> 4x64, concat, ELU (A = fp32 x, in-register convert)
  k_gemm_mfma<128, 4, 128, true><<<GB, 512, 0, stream>>>(
      x, W1t, as1, ad1, hq1, aS, aD, N_NODES);
  k_aggr<4, true, true, false><<<(N_NODES + 3) / 4, 256, 0, stream>>>(
      rowptr, csr, hq1, aS, aD, b1, hBq,
      nullptr, nullptr, nullptr, nullptr, nullptr, nullptr);

  // ---- layer 2: 256 -> 2x64, concat, ELU; epilogue fuses layer-3 projection
  k_gemm_mfma<256, 2, 128, false><<<GB, 512, 0, stream>>>(
      hBq, W2t, as2, ad2, hq2, aS, aD, N_NODES);
  k_aggr<2, true, false, true><<<(N_NODES + 3) / 4, 256, 0, stream>>>(
      rowptr, csr, hq2, aS, aD, b2, nullptr,
      W3, as3, ad3, h3, a3s, a3d);

  // ---- layer 3 aggregate + log_softmax
  k_aggr3<<<(N_NODES + 255) / 256, 256, 0, stream>>>(rowptr, csr, h3, a3s, a3d, b3, out);
}